// Round 3
// baseline (316.589 us; speedup 1.0000x reference)
//
#include <hip/hip_runtime.h>
#include <hip/hip_bf16.h>

typedef float f32x4 __attribute__((ext_vector_type(4)));
typedef short s16x8 __attribute__((ext_vector_type(8)));
typedef short s16x4 __attribute__((ext_vector_type(4)));
typedef __bf16 bf16x8 __attribute__((ext_vector_type(8)));
typedef unsigned short u16;

#define DEVI __device__ __forceinline__

static constexpr int    HW      = 16384;
static constexpr size_t BSTRIDE = (size_t)256 * HW;

// ---- workspace byte offsets ----
static constexpr size_t oXBT   = 0;                                    // bf16 [8][HW][256]
static constexpr size_t oEK    = oXBT  + (size_t)8 * HW * 256 * 2;     // bf16 [8][256][HW] exp(keys)
static constexpr size_t oQT    = oEK   + (size_t)8 * 256 * HW * 2;     // bf16 [8][HW][256] softmaxed Q, transposed
static constexpr size_t oVB    = oQT   + (size_t)8 * HW * 256 * 2;     // bf16 [8][256][HW]
static constexpr size_t oWK    = oVB   + (size_t)8 * 256 * HW * 2;     // bf16 [768][256]
static constexpr size_t oBIAS  = oWK   + (size_t)768 * 256 * 2;        // f32 [768]
static constexpr size_t oISE   = oBIAS + 4096;                         // f32 [8][256] inv row-sum-exp
static constexpr size_t oPS    = oISE  + 8192;                         // f32 [256][8][256] rowsum partials
static constexpr size_t oCTX   = oPS   + (size_t)256 * 2048 * 4;       // f32 [64][32][32]
static constexpr size_t oMB    = oCTX  + (size_t)64 * 1024 * 4;        // bf16 [8][256][256]
static constexpr size_t oCPART = oMB   + (size_t)8 * 256 * 256 * 2;    // f32 [4096][1024]
static constexpr size_t oMPART = oCPART + (size_t)4096 * 1024 * 4;     // f32 [8][8][HW]

DEVI float bf2f(short x) {
  unsigned u = ((unsigned)(unsigned short)x) << 16;
  return __builtin_bit_cast(float, u);
}
DEVI u16 f2bf(float x) { return __builtin_bit_cast(u16, (__bf16)x); }

DEVI void gld16(const void* g, void* l) {
  __builtin_amdgcn_global_load_lds(
      (__attribute__((address_space(1))) void*)(g),
      (__attribute__((address_space(3))) void*)(l), 16, 0, 0);
}

DEVI void cfence() { asm volatile("" ::: "memory"); }

// ---------------- prep: pack Wk|Wq|Wv -> bf16 [768][256], biases -> f32 [768] ----------------
__global__ __launch_bounds__(256) void k_prep(
    const float* __restrict__ Wk, const float* __restrict__ Wq, const float* __restrict__ Wv,
    const float* __restrict__ bk, const float* __restrict__ bq, const float* __restrict__ bv,
    u16* __restrict__ Wkqv, float* __restrict__ bias)
{
  int i = blockIdx.x * 256 + threadIdx.x;
  for (int p = i; p < 768 * 256; p += 64 * 256) {
    float v = (p < 65536) ? Wk[p] : (p < 131072 ? Wq[p - 65536] : Wv[p - 131072]);
    Wkqv[p] = f2bf(v);
  }
  if (i < 768) bias[i] = (i < 256) ? bk[i] : (i < 512 ? bq[i - 256] : bv[i - 512]);
}

// ---------------- transpose x [8][256][HW] f32 -> bf16 [8][HW][256] ----------------
__global__ __launch_bounds__(256) void k_transpose(const float* __restrict__ in_, u16* __restrict__ out)
{
  __shared__ u16 lds[64 * 256];
  const int t = threadIdx.x;
  const int n = blockIdx.y;
  const int s0 = blockIdx.x * 64;
  const float* src = in_ + ((size_t)n * 256 + t) * HW + s0;
  #pragma unroll
  for (int i = 0; i < 16; ++i) {
    f32x4 v = *(const f32x4*)(src + i * 4);
    #pragma unroll
    for (int j = 0; j < 4; ++j) lds[(i * 4 + j) * 256 + t] = f2bf(v[j]);
  }
  __syncthreads();
  s16x8* gp = (s16x8*)(out + (size_t)n * BSTRIDE + (size_t)s0 * 256);
  const s16x8* lp = (const s16x8*)lds;
  #pragma unroll
  for (int i = 0; i < 8; ++i) gp[t + i * 256] = lp[t + i * 256];
}

// ---------------- 256x256xK256 pipelined MFMA GEMM, 8 waves, BK=64, swizzled LDS ----------------
// MODE 0: fused projections, mb 0=exp(keys)+rowsum, 1=softmax-Q transposed, 2=values
// MODE 1: attn = Mb * qT^T + br, f32 out
template<int MODE>
__global__ __launch_bounds__(512, 2) void k_gemm256(
    const u16* __restrict__ A, const u16* __restrict__ B, const float* __restrict__ bias,
    u16* __restrict__ o_ek, u16* __restrict__ o_qT, u16* __restrict__ o_vb,
    float* __restrict__ o_ps, float* __restrict__ o_f32)
{
  __shared__ u16 smem[65536];          // 128 KiB: A dbuf [2][256][64] | B dbuf [2][256][64]
  const int t = threadIdx.x;
  const int L = blockIdx.x;
  const int n = L & 7;                 // one batch per XCD
  const int idx = L >> 3;
  int mb, sb;
  if constexpr (MODE == 0) { mb = idx % 3; sb = idx / 3; }   // k/q/v blocks adjacent -> B-panel L2 reuse
  else                     { mb = 0;       sb = idx; }
  const int s0 = sb * 256;
  const int lane = t & 63;
  const int l15 = lane & 15, l4 = lane >> 4;
  const int w = t >> 6;
  const int wr = w & 1, wc = w >> 1;   // wave tile: rows wr*128..+128, cols wc*64..+64
  const int tr = t >> 3;               // staging row within 64-row group
  const int csw = (t & 7) ^ (tr & 7);  // pre-swizzled source chunk

  const u16* Ag = A + (MODE == 0 ? (size_t)mb * 65536 : (size_t)n * 65536);
  const u16* Bg = B + (size_t)n * BSTRIDE + (size_t)s0 * 256;

  auto STAGE = [&](int buf, int kt) {
    const int k0 = kt * 64 + csw * 8;
    #pragma unroll
    for (int i = 0; i < 4; ++i) {
      const size_t r = (size_t)(i * 64 + tr);
      gld16(Ag + r * 256 + k0, smem + buf * 16384 + (i * 512 + t) * 8);
      gld16(Bg + r * 256 + k0, smem + 32768 + buf * 16384 + (i * 512 + t) * 8);
    }
  };

  f32x4 acc[8][4] = {};

  auto COMPUTE = [&](int buf) {
    const u16* Al = smem + buf * 16384;
    const u16* Bl = smem + 32768 + buf * 16384;
    bf16x8 bf[4][2];
    #pragma unroll
    for (int b = 0; b < 4; ++b) {
      const int s = wc * 64 + b * 16 + l15;
      #pragma unroll
      for (int ks = 0; ks < 2; ++ks)
        bf[b][ks] = *(const bf16x8*)&Bl[s * 64 + ((ks * 4 + l4) ^ (s & 7)) * 8];
    }
    #pragma unroll
    for (int p = 0; p < 4; ++p) {
      bf16x8 af[2][2];
      #pragma unroll
      for (int a2 = 0; a2 < 2; ++a2) {
        const int m = wr * 128 + (p * 2 + a2) * 16 + l15;
        #pragma unroll
        for (int ks = 0; ks < 2; ++ks)
          af[a2][ks] = *(const bf16x8*)&Al[m * 64 + ((ks * 4 + l4) ^ (m & 7)) * 8];
      }
      __builtin_amdgcn_s_setprio(1);
      #pragma unroll
      for (int a2 = 0; a2 < 2; ++a2)
        #pragma unroll
        for (int b = 0; b < 4; ++b)
          #pragma unroll
          for (int ks = 0; ks < 2; ++ks)
            acc[p * 2 + a2][b] = __builtin_amdgcn_mfma_f32_16x16x32_bf16(
                af[a2][ks], bf[b][ks], acc[p * 2 + a2][b], 0, 0, 0);
      __builtin_amdgcn_s_setprio(0);
    }
  };

  STAGE(0, 0); STAGE(1, 1);            // 16 vm-ops in flight per thread
  #pragma unroll
  for (int kt = 0; kt < 4; ++kt) {
    if (kt < 3) asm volatile("s_waitcnt vmcnt(8)" ::: "memory");
    else        asm volatile("s_waitcnt vmcnt(0)" ::: "memory");
    cfence(); __builtin_amdgcn_s_barrier(); cfence();
    COMPUTE(kt & 1);
    asm volatile("s_waitcnt lgkmcnt(0)" ::: "memory");   // reads done before buffer reuse
    cfence(); __builtin_amdgcn_s_barrier(); cfence();
    if (kt < 2) STAGE(kt & 1, kt + 2);                   // overwrite only after all waves done reading
  }
  __syncthreads();

  // -------- epilogues (acc[am][b][r]: m = wr*128+am*16+l4*4+r, s = s0+wc*64+b*16+l15) --------
  if constexpr (MODE == 1) {
    float* O = o_f32 + (size_t)n * BSTRIDE;
    #pragma unroll
    for (int am = 0; am < 8; ++am)
      #pragma unroll
      for (int r = 0; r < 4; ++r) {
        const int m = wr * 128 + am * 16 + l4 * 4 + r;
        const float bb = bias[m];
        float* op = O + (size_t)m * HW + s0 + wc * 64 + l15;
        #pragma unroll
        for (int b = 0; b < 4; ++b) op[b * 16] = acc[am][b][r] + bb;
      }
    return;
  } else {
  if (mb == 0) {
    // exp(keys) + deterministic rowsum partials
    float* psrow = o_ps + ((size_t)(sb * 4 + wc) * 8 + n) * 256;
    u16* O = o_ek + (size_t)n * BSTRIDE;
    #pragma unroll
    for (int am = 0; am < 8; ++am)
      #pragma unroll
      for (int r = 0; r < 4; ++r) {
        const int m = wr * 128 + am * 16 + l4 * 4 + r;
        const float bb = bias[m];
        const float e0 = __expf(acc[am][0][r] + bb), e1 = __expf(acc[am][1][r] + bb);
        const float e2 = __expf(acc[am][2][r] + bb), e3 = __expf(acc[am][3][r] + bb);
        float s_ = e0 + e1 + e2 + e3;
        s_ += __shfl_xor(s_, 1); s_ += __shfl_xor(s_, 2);
        s_ += __shfl_xor(s_, 4); s_ += __shfl_xor(s_, 8);
        if (l15 == 0) psrow[m] = s_;
        u16* op = O + (size_t)m * HW + s0 + wc * 64 + l15;
        op[0] = f2bf(e0); op[16] = f2bf(e1); op[32] = f2bf(e2); op[48] = f2bf(e3);
      }
  } else if (mb == 1) {
    // per-head (32-row) softmax over m, then transposed store qT[n][s][m]
    #pragma unroll
    for (int am = 0; am < 8; ++am)
      #pragma unroll
      for (int r = 0; r < 4; ++r) {
        const float bb = bias[256 + wr * 128 + am * 16 + l4 * 4 + r];
        #pragma unroll
        for (int b = 0; b < 4; ++b) acc[am][b][r] += bb;
      }
    #pragma unroll
    for (int hh = 0; hh < 4; ++hh)
      #pragma unroll
      for (int b = 0; b < 4; ++b) {
        float s = 0.f;
        #pragma unroll
        for (int a2 = 0; a2 < 2; ++a2)
          #pragma unroll
          for (int r = 0; r < 4; ++r) {
            const float e = __expf(acc[hh * 2 + a2][b][r]);
            acc[hh * 2 + a2][b][r] = e; s += e;
          }
        s += __shfl_xor(s, 16); s += __shfl_xor(s, 32);
        const float inv = 1.f / s;
        #pragma unroll
        for (int a2 = 0; a2 < 2; ++a2)
          #pragma unroll
          for (int r = 0; r < 4; ++r) acc[hh * 2 + a2][b][r] *= inv;
      }
    // transposed store via LDS overlay, two 128-row halves (tile [128][264] u16)
    #pragma unroll
    for (int H = 0; H < 2; ++H) {
      if ((wc >> 1) == H) {
        #pragma unroll
        for (int am = 0; am < 8; ++am)
          #pragma unroll
          for (int b = 0; b < 4; ++b) {
            const int srow = wc * 64 + b * 16 + l15 - H * 128;
            s16x4 pk;
            #pragma unroll
            for (int r = 0; r < 4; ++r) pk[r] = (short)f2bf(acc[am][b][r]);
            *(s16x4*)&smem[srow * 264 + wr * 128 + am * 16 + l4 * 4] = pk;
          }
      }
      __syncthreads();
      const int row = t >> 2;
      const int cq = (t & 3) * 64;
      u16* dst = o_qT + (size_t)n * BSTRIDE + (size_t)(s0 + H * 128 + row) * 256 + cq;
      const u16* srcl = smem + row * 264 + cq;
      #pragma unroll
      for (int i = 0; i < 8; ++i) *(s16x8*)(dst + i * 8) = *(const s16x8*)(srcl + i * 8);
      __syncthreads();
    }
  } else {
    // values: plain bf16 store
    u16* O = o_vb + (size_t)n * BSTRIDE;
    #pragma unroll
    for (int am = 0; am < 8; ++am)
      #pragma unroll
      for (int r = 0; r < 4; ++r) {
        const int m = wr * 128 + am * 16 + l4 * 4 + r;
        const float bb = bias[512 + m];
        u16* op = O + (size_t)m * HW + s0 + wc * 64 + l15;
        #pragma unroll
        for (int b = 0; b < 4; ++b) op[b * 16] = f2bf(acc[am][b][r] + bb);
      }
  }
  }
}

// ---------------- reduce rowsum partials -> inverse ----------------
__global__ __launch_bounds__(256) void k_inv(const float* __restrict__ ps, float* __restrict__ ise)
{
  const int i = blockIdx.x * 256 + threadIdx.x;   // 2048
  float s = 0.f;
  for (int b = 0; b < 256; ++b) s += ps[(size_t)b * 2048 + i];
  ise[i] = 1.f / s;
}

// ---------------- ctx split-K partials + fused attention-map partials ----------------
__global__ __launch_bounds__(64) void k_ctx_part(
    const u16* __restrict__ ek, const u16* __restrict__ vb, const float* __restrict__ ise,
    float* __restrict__ cpart, float* __restrict__ mpart)
{
  const int blk = blockIdx.x;            // nh*64 + chunk
  const int chunk = blk & 63, nh = blk >> 6;
  const int h = nh & 7, n = nh >> 3;
  const int lane = threadIdx.x;
  const int l15 = lane & 15, l4 = lane >> 4;
  const u16* kb = ek + ((size_t)n * 256 + h * 32) * HW;
  const u16* vv = vb + ((size_t)n * 256 + h * 32) * HW;
  const float iv0 = ise[n * 256 + h * 32 + l15];
  const float iv1 = ise[n * 256 + h * 32 + 16 + l15];
  f32x4 acc[2][2] = {};
  float macc[8][8] = {};
  const int sbase = chunk * 256 + l4 * 8;
  #pragma unroll
  for (int ks = 0; ks < 8; ++ks) {
    const int sb = sbase + ks * 32;
    bf16x8 ef[2], vf[2];
    #pragma unroll
    for (int g = 0; g < 2; ++g) {
      ef[g] = *(const bf16x8*)(kb + (size_t)(g * 16 + l15) * HW + sb);
      vf[g] = *(const bf16x8*)(vv + (size_t)(g * 16 + l15) * HW + sb);
    }
    #pragma unroll
    for (int j = 0; j < 8; ++j)
      macc[ks][j] = fmaf(iv0, (float)ef[0][j], fmaf(iv1, (float)ef[1][j], macc[ks][j]));
    #pragma unroll
    for (int a = 0; a < 2; ++a)
      #pragma unroll
      for (int b = 0; b < 2; ++b)
        acc[a][b] = __builtin_amdgcn_mfma_f32_16x16x32_bf16(ef[a], vf[b], acc[a][b], 0, 0, 0);
  }
  float* op = cpart + (size_t)blk * 1024;
  #pragma unroll
  for (int a = 0; a < 2; ++a)
    #pragma unroll
    for (int b = 0; b < 2; ++b)
      #pragma unroll
      for (int r = 0; r < 4; ++r)
        op[(a * 16 + l4 * 4 + r) * 32 + b * 16 + l15] = acc[a][b][r];
  #pragma unroll
  for (int ks = 0; ks < 8; ++ks)
    #pragma unroll
    for (int j = 0; j < 8; ++j) {
      float v = macc[ks][j];
      v += __shfl_xor(v, 1); v += __shfl_xor(v, 2);
      v += __shfl_xor(v, 4); v += __shfl_xor(v, 8);
      macc[ks][j] = v;
    }
  if (l15 == 0) {
    float* mp = mpart + ((size_t)h * 8 + n) * HW + sbase;
    #pragma unroll
    for (int ks = 0; ks < 8; ++ks) {
      f32x4 a = {macc[ks][0], macc[ks][1], macc[ks][2], macc[ks][3]};
      f32x4 b = {macc[ks][4], macc[ks][5], macc[ks][6], macc[ks][7]};
      *(f32x4*)(mp + ks * 32)     = a;
      *(f32x4*)(mp + ks * 32 + 4) = b;
    }
  }
}

// ---------------- reduce ctx partials, normalize; emit context_last (h==7) ----------------
__global__ __launch_bounds__(256) void k_ctx_reduce(
    const float* __restrict__ cpart, const float* __restrict__ ise,
    float* __restrict__ ctx, float* __restrict__ dctx)
{
  const int nh = blockIdx.x, n = nh >> 3, h = nh & 7, t = threadIdx.x;
  f32x4 a = {};
  for (int c = 0; c < 64; ++c) a += *(const f32x4*)(cpart + ((size_t)nh * 64 + c) * 1024 + t * 4);
  const float inv = ise[n * 256 + h * 32 + (t >> 3)];
  a *= inv;
  *(f32x4*)(ctx + (size_t)nh * 1024 + t * 4) = a;
  if (h == 7) *(f32x4*)(dctx + (size_t)n * 1024 + t * 4) = a;
}

// ---------------- M[n][o][h*32+k] = sum_v Wr[o][h*32+v] * ctx[n][h][k][v] ----------------
__global__ __launch_bounds__(256) void k_mmat(
    const float* __restrict__ ctx, const float* __restrict__ Wr, u16* __restrict__ Mb)
{
  const int nh = blockIdx.x, n = nh >> 3, h = nh & 7, o = threadIdx.x;
  __shared__ float cl[1024];
  #pragma unroll
  for (int i = 0; i < 4; ++i) cl[o + i * 256] = ctx[(size_t)nh * 1024 + o + i * 256];
  __syncthreads();
  float wr[32];
  const float* wp = Wr + (size_t)o * 256 + h * 32;
  #pragma unroll
  for (int v = 0; v < 32; ++v) wr[v] = wp[v];
  u16* mp = Mb + ((size_t)n * 256 + o) * 256 + h * 32;
  #pragma unroll 4
  for (int k = 0; k < 32; ++k) {
    float s = 0.f;
    #pragma unroll
    for (int v = 0; v < 32; ++v) s += wr[v] * cl[k * 32 + v];
    mp[k] = f2bf(s);
  }
}

// ---------------- attention_map: sum 8 head partials, /256 ----------------
__global__ __launch_bounds__(256) void k_map_reduce(const float* __restrict__ mpart, float* __restrict__ dmap)
{
  const int i = blockIdx.x * 256 + threadIdx.x;   // 32768 threads, f32x4 each
  f32x4 a = {};
  #pragma unroll
  for (int h = 0; h < 8; ++h) a += *(const f32x4*)(mpart + (size_t)h * 131072 + (size_t)i * 4);
  a *= (1.0f / 256.0f);
  *(f32x4*)(dmap + (size_t)i * 4) = a;
}

extern "C" void kernel_launch(void* const* d_in, const int* in_sizes, int n_in,
                              void* d_out, int out_size, void* d_ws, size_t ws_size,
                              hipStream_t stream)
{
  (void)in_sizes; (void)n_in; (void)out_size; (void)ws_size;
  const float* x  = (const float*)d_in[0];
  const float* Wk = (const float*)d_in[1];
  const float* bk = (const float*)d_in[2];
  const float* Wq = (const float*)d_in[3];
  const float* bq = (const float*)d_in[4];
  const float* Wv = (const float*)d_in[5];
  const float* bv = (const float*)d_in[6];
  const float* Wr = (const float*)d_in[7];
  const float* br = (const float*)d_in[8];

  char* ws = (char*)d_ws;
  u16*   xbT  = (u16*)(ws + oXBT);
  u16*   ek   = (u16*)(ws + oEK);
  u16*   qT   = (u16*)(ws + oQT);
  u16*   vb   = (u16*)(ws + oVB);
  u16*   Wkqv = (u16*)(ws + oWK);
  float* bias = (float*)(ws + oBIAS);
  float* ise  = (float*)(ws + oISE);
  float* ps   = (float*)(ws + oPS);
  float* ctx  = (float*)(ws + oCTX);
  u16*   Mb   = (u16*)(ws + oMB);
  float* cpart= (float*)(ws + oCPART);
  float* mpart= (float*)(ws + oMPART);

  float* attn = (float*)d_out;                    // [8][256][HW]
  float* dctx = (float*)d_out + 33554432;         // [8][32][32]
  float* dmap = (float*)d_out + 33562624;         // [8][HW]

  k_prep<<<64, 256, 0, stream>>>(Wk, Wq, Wv, bk, bq, bv, Wkqv, bias);
  k_transpose<<<dim3(256, 8), 256, 0, stream>>>(x, xbT);
  k_gemm256<0><<<1536, 512, 0, stream>>>(Wkqv, xbT, bias, ek, qT, vb, ps, nullptr);
  k_inv<<<8, 256, 0, stream>>>(ps, ise);
  k_ctx_part<<<4096, 64, 0, stream>>>(ek, vb, ise, cpart, mpart);
  k_ctx_reduce<<<64, 256, 0, stream>>>(cpart, ise, ctx, dctx);
  k_mmat<<<64, 256, 0, stream>>>(ctx, Wr, Mb);
  k_map_reduce<<<128, 256, 0, stream>>>(mpart, dmap);
  k_gemm256<1><<<512, 512, 0, stream>>>(Mb, qT, br, nullptr, nullptr, nullptr, nullptr, attn);
}